// Round 1
// baseline (473.833 us; speedup 1.0000x reference)
//
#include <hip/hip_runtime.h>
#include <hip/hip_bf16.h>

// ---------------------------------------------------------------------------
// DatasetScoreMatchingLoss — emulates np's fp32 sequential segment_sum via
// quantized contributions c_i = u*rint(x_i/u), u = ulp of the running-prefix
// binade, predicted per chunk by a linear model (exclusive chunk prefix +
// mean rate). Round 5: kernel was latency-bound (VALU 17%, HBM 13%, LDS 3%).
// (a) LDS slot accumulation now uses fire-and-forget ds_add_f32 (atomicAdd on
//     per-thread-private rows: no contention, program-order adds -> bitwise
//     identical sums) removing the read->lgkmcnt->add->write round trip.
// (b) Full-chunk blocks run an unguarded loop with 1-deep register prefetch
//     of next iteration's global loads (the old in-loop `break` blocked all
//     load/compute overlap). Guarded path kept for ragged tails.
// Arithmetic order (quad merge, reductions, scan, model, epilogue) unchanged.
// ---------------------------------------------------------------------------

#define TBL   65536u
#define TBLM  (TBL - 1u)
#define NGR   12            // actual group ids in [0,12)
#define NBK   24            // 12 groups x 2 labels
#define NCOL  25            // +1 dummy column (invalid / merged-away)
#define NTHR  256
#define CHUNK 16384
#define ITER  (CHUNK / 4 / NTHR)
#define MINC  10.0

__device__ __forceinline__ unsigned hash_idx(unsigned idx) {
    return (idx * 2654435761u) & TBLM;
}

// --- Phase 1: vote for last writer (max batch pos) + mark bitmap ------------
__global__ void k_vote(const int* __restrict__ indices,
                       unsigned long long* __restrict__ table,
                       unsigned* __restrict__ bitmap, int B) {
    int b = blockIdx.x * blockDim.x + threadIdx.x;
    if (b >= B) return;
    unsigned idx = (unsigned)indices[b];
    atomicOr(&bitmap[idx >> 5], 1u << (idx & 31u));
    unsigned long long key = ((unsigned long long)(idx + 1u)) << 32;
    unsigned long long val = key | (unsigned long long)(unsigned)b;
    unsigned slot = hash_idx(idx);
    for (;;) {
        unsigned long long prev = atomicCAS(&table[slot], 0ULL, val);
        if (prev == 0ULL) return;
        if ((prev >> 32) == (unsigned long long)(idx + 1u)) {
            atomicMax(&table[slot], val);
            return;
        }
        slot = (slot + 1u) & TBLM;
    }
}

// Resolve override directly from table + batch arrays (rare: ~32K/16.7M).
__device__ __forceinline__ void apply_ovr(int idx, float& s, int& l, int& g,
        const unsigned long long* __restrict__ table,
        const float* __restrict__ probs, const int* __restrict__ labels,
        const int* __restrict__ groups) {
    unsigned slot = hash_idx((unsigned)idx);
    unsigned hi = (unsigned)idx + 1u;
    for (;;) {
        unsigned long long e = table[slot];
        if ((unsigned)(e >> 32) == hi) {
            int b = (int)(e & 0xffffffffu);
            s = probs[b]; l = labels[b]; g = groups[b];
            return;
        }
        slot = (slot + 1u) & TBLM;
    }
}

// --- quad processing for pass1 (sum only) -----------------------------------
__device__ __forceinline__ void quad_p1(float* __restrict__ row,
        float4 s4, int4 l4, int4 g4, unsigned bits, int v,
        const unsigned long long* __restrict__ table,
        const float* __restrict__ probs, const int* __restrict__ labels,
        const int* __restrict__ groups) {
    float ss[4] = {s4.x, s4.y, s4.z, s4.w};
    int   ll[4] = {l4.x, l4.y, l4.z, l4.w};
    int   gg[4] = {g4.x, g4.y, g4.z, g4.w};
    float val[4]; int bkt[4];
#pragma unroll
    for (int e = 0; e < 4; ++e) {
        float s = ss[e]; int l = ll[e], g = gg[e];
        if ((bits >> e) & 1u)
            apply_ovr((v << 2) + e, s, l, g, table, probs, labels, groups);
        bool valid = (s == s) && ((unsigned)l < 2u) && ((unsigned)g < (unsigned)NGR);
        bkt[e] = valid ? (g * 2 + l) : NBK;
        val[e] = valid ? s : 0.f;
    }
    // merge intra-quad duplicates (same order as before -> bitwise identical)
#define MRG(i, j) { bool m_ = (bkt[i] == bkt[j]); \
                    val[i] += m_ ? val[j] : 0.f;  \
                    bkt[j] = m_ ? NBK : bkt[j];   \
                    val[j] = m_ ? 0.f : val[j]; }
    MRG(0,1) MRG(0,2) MRG(0,3) MRG(1,2) MRG(1,3) MRG(2,3)
#undef MRG
    // fire-and-forget ds_add_f32: per-thread-private slots, no contention,
    // same-thread DS ops execute in order -> sums bitwise identical.
    atomicAdd(&row[bkt[0]], val[0]);
    atomicAdd(&row[bkt[1]], val[1]);
    atomicAdd(&row[bkt[2]], val[2]);
    atomicAdd(&row[bkt[3]], val[3]);
}

// --- Phase 2: per-chunk fp32 bucket sums (LDS slots) ------------------------
__global__ __launch_bounds__(NTHR) void k_pass1(
        const float* __restrict__ sb, const int* __restrict__ lb,
        const int* __restrict__ gb, const unsigned* __restrict__ bitmap,
        const unsigned long long* __restrict__ table,
        const float* __restrict__ probs, const int* __restrict__ labels,
        const int* __restrict__ groups,
        float* __restrict__ bsum, int n, int nblk) {
    __shared__ float s_acc[NTHR * NCOL];      // 25.6 KB
    int tid = threadIdx.x, blk = blockIdx.x;
    for (int i = tid; i < NTHR * NCOL; i += NTHR) s_acc[i] = 0.f;
    __syncthreads();
    float* row = &s_acc[tid * NCOL];
    int vbase = (blk * CHUNK) >> 2, nv = n >> 2;
    if (vbase + (CHUNK >> 2) <= nv) {
        // full chunk: no per-iteration bounds check, 1-deep load prefetch
        int v = vbase + tid;
        float4 s4 = ((const float4*)sb)[v];
        int4   l4 = ((const int4*)lb)[v];
        int4   g4 = ((const int4*)gb)[v];
        unsigned bits = bitmap[v >> 3] >> ((v & 7) * 4);
#pragma unroll 2
        for (int it = 0; it < ITER; ++it) {
            float4 s4c = s4; int4 l4c = l4, g4c = g4;
            unsigned bitsc = bits; int vc = v;
            if (it + 1 < ITER) {            // issue next loads BEFORE compute
                v += NTHR;
                s4 = ((const float4*)sb)[v];
                l4 = ((const int4*)lb)[v];
                g4 = ((const int4*)gb)[v];
                bits = bitmap[v >> 3] >> ((v & 7) * 4);
            }
            quad_p1(row, s4c, l4c, g4c, bitsc, vc, table, probs, labels, groups);
        }
    } else {
        for (int it = 0; it < ITER; ++it) {
            int v = vbase + it * NTHR + tid;
            if (v >= nv) break;
            float4 s4 = ((const float4*)sb)[v];
            int4   l4 = ((const int4*)lb)[v];
            int4   g4 = ((const int4*)gb)[v];
            unsigned bits = bitmap[v >> 3] >> ((v & 7) * 4);
            quad_p1(row, s4, l4, g4, bits, v, table, probs, labels, groups);
        }
    }
    // scalar tail (n % 4) — last block only
    if (blk == nblk - 1) {
        for (int i = (nv << 2) + tid; i < n; i += NTHR) {
            float s = sb[i]; int l = lb[i], g = gb[i];
            if ((bitmap[i >> 5] >> (i & 31)) & 1u)
                apply_ovr(i, s, l, g, table, probs, labels, groups);
            bool valid = (s == s) && ((unsigned)l < 2u) && ((unsigned)g < (unsigned)NGR);
            int bk = valid ? (g * 2 + l) : NBK;
            atomicAdd(&row[bk], valid ? s : 0.f);
        }
    }
    __syncthreads();
    if (tid < NBK * 8) {
        int bkt = tid >> 3, sub = tid & 7;
        float sm = 0.f;
        for (int j = 0; j < 32; ++j) sm += s_acc[(sub * 32 + j) * NCOL + bkt];
        for (int d = 4; d >= 1; d >>= 1) sm += __shfl_down(sm, d, 8);
        if (!sub) bsum[bkt * nblk + blk] = sm;
    }
}

// --- Phase 2.5: exclusive scan, one block per bucket (fp64) -----------------
__global__ void k_scan(const float* __restrict__ bsum,
                       float* __restrict__ bpref, int nblk) {
    __shared__ double sc[NTHR];
    int t = threadIdx.x, k = blockIdx.x;
    const float* src = bsum  + (size_t)k * nblk;
    float*       dst = bpref + (size_t)k * nblk;
    double carry = 0.0;
    for (int s0 = 0; s0 < nblk; s0 += 4 * NTHR) {
        int i0 = s0 + 4 * t;
        float x0 = (i0 + 0 < nblk) ? src[i0 + 0] : 0.f;
        float x1 = (i0 + 1 < nblk) ? src[i0 + 1] : 0.f;
        float x2 = (i0 + 2 < nblk) ? src[i0 + 2] : 0.f;
        float x3 = (i0 + 3 < nblk) ? src[i0 + 3] : 0.f;
        double p0 = (double)x0, p1 = p0 + x1, p2 = p1 + x2, tot = p2 + x3;
        sc[t] = tot;
        __syncthreads();
        for (int st = 1; st < NTHR; st <<= 1) {
            double a = (t >= st) ? sc[t - st] : 0.0;
            __syncthreads();
            sc[t] += a;
            __syncthreads();
        }
        double excl = carry + sc[t] - tot;
        if (i0 + 0 < nblk) dst[i0 + 0] = (float)excl;
        if (i0 + 1 < nblk) dst[i0 + 1] = (float)(excl + p0);
        if (i0 + 2 < nblk) dst[i0 + 2] = (float)(excl + p1);
        if (i0 + 3 < nblk) dst[i0 + 3] = (float)(excl + p2);
        double bt = sc[NTHR - 1];
        __syncthreads();
        carry += bt;
    }
}

__device__ __forceinline__ double aload_d(const double* p) {
    unsigned long long u = __hip_atomic_load((const unsigned long long*)p,
                              __ATOMIC_RELAXED, __HIP_MEMORY_SCOPE_AGENT);
    return __longlong_as_double((long long)u);
}

// --- quad processing for pass2 (quantized contribution + count) -------------
__device__ __forceinline__ void quad_p2(float* __restrict__ rowf,
        const float2* __restrict__ s_model,
        float4 s4, int4 l4, int4 g4, unsigned bits, int v, int base,
        const unsigned long long* __restrict__ table,
        const float* __restrict__ probs, const int* __restrict__ labels,
        const int* __restrict__ groups) {
    float ss[4] = {s4.x, s4.y, s4.z, s4.w};
    int   ll[4] = {l4.x, l4.y, l4.z, l4.w};
    int   gg[4] = {g4.x, g4.y, g4.z, g4.w};
    float cv[4], cn[4]; int bkt[4];
#pragma unroll
    for (int e = 0; e < 4; ++e) {
        int idx = (v << 2) + e;
        float s = ss[e]; int l = ll[e], g = gg[e];
        if ((bits >> e) & 1u)
            apply_ovr(idx, s, l, g, table, probs, labels, groups);
        bool valid = (s == s) && ((unsigned)l < 2u) && ((unsigned)g < (unsigned)NGR);
        int bk = valid ? (g * 2 + l) : NBK;
        float2 m = s_model[bk];
        float S = fmaf(m.y, (float)(idx - base), m.x);
        float T = S + s;                          // post-add binade probe
        unsigned ue = __float_as_uint(T) & 0x7f800000u;
        float c;
        if (ue < (24u << 23)) c = s;              // tiny/zero prefix
        else {
            unsigned ub = ue - (23u << 23);       // u = ulp = 2^(e-150)
            float u    = __uint_as_float(ub);
            float uinv = __uint_as_float((254u << 23) - ub);
            c = u * rintf(s * uinv);
        }
        bkt[e] = bk;
        cv[e] = valid ? c : 0.f;
        cn[e] = valid ? 1.f : 0.f;
    }
#define MRG(i, j) { bool m_ = (bkt[i] == bkt[j]); \
                    cv[i] += m_ ? cv[j] : 0.f;    \
                    cn[i] += m_ ? cn[j] : 0.f;    \
                    bkt[j] = m_ ? NBK : bkt[j];   \
                    cv[j] = m_ ? 0.f : cv[j];     \
                    cn[j] = m_ ? 0.f : cn[j]; }
    MRG(0,1) MRG(0,2) MRG(0,3) MRG(1,2) MRG(1,3) MRG(2,3)
#undef MRG
    atomicAdd(&rowf[2 * bkt[0] + 0], cv[0]);
    atomicAdd(&rowf[2 * bkt[0] + 1], cn[0]);
    atomicAdd(&rowf[2 * bkt[1] + 0], cv[1]);
    atomicAdd(&rowf[2 * bkt[1] + 1], cn[1]);
    atomicAdd(&rowf[2 * bkt[2] + 0], cv[2]);
    atomicAdd(&rowf[2 * bkt[2] + 1], cn[2]);
    atomicAdd(&rowf[2 * bkt[3] + 0], cv[3]);
    atomicAdd(&rowf[2 * bkt[3] + 1], cn[3]);
}

// --- Phase 3: quantized contributions + counts (LDS float2 slots) -----------
// Last block to finish runs the fp64 epilogue and writes out[0].
__global__ __launch_bounds__(NTHR) void k_pass2(
        const float* __restrict__ sb, const int* __restrict__ lb,
        const int* __restrict__ gb, const unsigned* __restrict__ bitmap,
        const unsigned long long* __restrict__ table,
        const float* __restrict__ probs, const int* __restrict__ labels,
        const int* __restrict__ groups,
        const float* __restrict__ bsum, const float* __restrict__ bpref,
        double* __restrict__ acc_sum, double* __restrict__ acc_cnt,
        unsigned* __restrict__ done, float* __restrict__ out,
        int n, int nblk) {
    __shared__ float2 s_acc[NTHR * NCOL];     // 51.2 KB: (c_sum, count)
    __shared__ float2 s_model[NCOL];          // (excl_prefix, rate)
    int tid = threadIdx.x, blk = blockIdx.x;
    for (int i = tid; i < NTHR * NCOL; i += NTHR) s_acc[i] = make_float2(0.f, 0.f);
    if (tid < NBK)
        s_model[tid] = make_float2(bpref[tid * nblk + blk],
                                   bsum[tid * nblk + blk] * (1.0f / CHUNK));
    if (tid == NBK) s_model[NBK] = make_float2(0.f, 0.f);
    __syncthreads();
    float* rowf = (float*)&s_acc[tid * NCOL];
    int base = blk * CHUNK;
    int vbase = base >> 2, nv = n >> 2;
    if (vbase + (CHUNK >> 2) <= nv) {
        // full chunk: no per-iteration bounds check, 1-deep load prefetch
        int v = vbase + tid;
        float4 s4 = ((const float4*)sb)[v];
        int4   l4 = ((const int4*)lb)[v];
        int4   g4 = ((const int4*)gb)[v];
        unsigned bits = bitmap[v >> 3] >> ((v & 7) * 4);
#pragma unroll 2
        for (int it = 0; it < ITER; ++it) {
            float4 s4c = s4; int4 l4c = l4, g4c = g4;
            unsigned bitsc = bits; int vc = v;
            if (it + 1 < ITER) {            // issue next loads BEFORE compute
                v += NTHR;
                s4 = ((const float4*)sb)[v];
                l4 = ((const int4*)lb)[v];
                g4 = ((const int4*)gb)[v];
                bits = bitmap[v >> 3] >> ((v & 7) * 4);
            }
            quad_p2(rowf, s_model, s4c, l4c, g4c, bitsc, vc, base,
                    table, probs, labels, groups);
        }
    } else {
        for (int it = 0; it < ITER; ++it) {
            int v = vbase + it * NTHR + tid;
            if (v >= nv) break;
            float4 s4 = ((const float4*)sb)[v];
            int4   l4 = ((const int4*)lb)[v];
            int4   g4 = ((const int4*)gb)[v];
            unsigned bits = bitmap[v >> 3] >> ((v & 7) * 4);
            quad_p2(rowf, s_model, s4, l4, g4, bits, v, base,
                    table, probs, labels, groups);
        }
    }
    if (blk == nblk - 1) {                            // scalar tail
        for (int i = (nv << 2) + tid; i < n; i += NTHR) {
            float s = sb[i]; int l = lb[i], g = gb[i];
            if ((bitmap[i >> 5] >> (i & 31)) & 1u)
                apply_ovr(i, s, l, g, table, probs, labels, groups);
            bool valid = (s == s) && ((unsigned)l < 2u) && ((unsigned)g < (unsigned)NGR);
            int bk = valid ? (g * 2 + l) : NBK;
            float2 m = s_model[bk];
            float S = fmaf(m.y, (float)(i - base), m.x);
            float T = S + s;
            unsigned ue = __float_as_uint(T) & 0x7f800000u;
            float c;
            if (ue < (24u << 23)) c = s;
            else {
                unsigned ub = ue - (23u << 23);
                float u    = __uint_as_float(ub);
                float uinv = __uint_as_float((254u << 23) - ub);
                c = u * rintf(s * uinv);
            }
            atomicAdd(&rowf[2 * bk + 0], valid ? c : 0.f);
            atomicAdd(&rowf[2 * bk + 1], valid ? 1.f : 0.f);
        }
    }
    __syncthreads();
    if (tid < NBK * 8) {
        int bkt = tid >> 3, sub = tid & 7;
        float sm = 0.f, cc = 0.f;
        for (int j = 0; j < 32; ++j) {
            float2 a = s_acc[(sub * 32 + j) * NCOL + bkt];
            sm += a.x; cc += a.y;
        }
        for (int d = 4; d >= 1; d >>= 1) {
            sm += __shfl_down(sm, d, 8);
            cc += __shfl_down(cc, d, 8);
        }
        if (!sub) {
            atomicAdd(&acc_sum[bkt], (double)sm);
            atomicAdd(&acc_cnt[bkt], (double)cc);
        }
    }
    __syncthreads();
    if (tid == 0) {
        __threadfence();
        unsigned r = __hip_atomic_fetch_add(done, 1u, __ATOMIC_ACQ_REL,
                                            __HIP_MEMORY_SCOPE_AGENT);
        if (r == (unsigned)(gridDim.x - 1)) {         // last block: epilogue
            double var[2], nn[2];
            for (int l = 0; l < 2; ++l) {
                double avg[NGR];
                double ncnt = 0.0, s = 0.0;
                for (int g = 0; g < NGR; ++g) {
                    double c  = aload_d(&acc_cnt[g * 2 + l]);
                    double sm = aload_d(&acc_sum[g * 2 + l]);
                    double a = sm / fmax(c, 1.0);
                    avg[g] = a;
                    if (c >= MINC) { ncnt += 1.0; s += a; }
                }
                double mean = s / fmax(ncnt, 1.0), v = 0.0;
                for (int g = 0; g < NGR; ++g) {
                    double c = aload_d(&acc_cnt[g * 2 + l]);
                    if (c >= MINC) { double d = avg[g] - mean; v += d * d; }
                }
                var[l] = v / fmax(ncnt - 1.0, 1.0);
                nn[l] = ncnt;
            }
            bool p = nn[1] >= 2.0, q = nn[0] >= 2.0;
            double loss = (p && q) ? 0.5 * (var[1] + var[0])
                        : (p ? var[1] : (q ? var[0] : 0.0));
            out[0] = (float)loss;
        }
    }
}

extern "C" void kernel_launch(void* const* d_in, const int* in_sizes, int n_in,
                              void* d_out, int out_size, void* d_ws, size_t ws_size,
                              hipStream_t stream) {
    const float* probs   = (const float*)d_in[0];
    const int*   labels  = (const int*)d_in[1];
    const int*   groups  = (const int*)d_in[2];
    const int*   indices = (const int*)d_in[3];
    const float* sb      = (const float*)d_in[4];
    const int*   lb      = (const int*)d_in[5];
    const int*   gb      = (const int*)d_in[6];
    int B = in_sizes[0];
    int n = in_sizes[4];
    int nblk   = (n + CHUNK - 1) / CHUNK;
    int nwords = (n + 31) / 32;

    // ws layout: [zeroed: table | bitmap | acc_sum | acc_cnt | done][rest]
    char* ws = (char*)d_ws;
    size_t off = 0;
    unsigned long long* table = (unsigned long long*)(ws + off); off += (size_t)TBL * 8;
    unsigned* bitmap  = (unsigned*)(ws + off); off += (size_t)nwords * 4;
    double*   acc_sum = (double*)(ws + off);   off += NBK * 8;
    double*   acc_cnt = (double*)(ws + off);   off += NBK * 8;
    unsigned* done    = (unsigned*)(ws + off); off += 8;
    size_t zero_bytes = off;
    float*    bsum    = (float*)(ws + off);    off += (size_t)nblk * NBK * 4;
    float*    bpref   = (float*)(ws + off);    off += (size_t)nblk * NBK * 4;

    hipMemsetAsync(d_ws, 0, zero_bytes, stream);

    dim3 bblk((B + NTHR - 1) / NTHR);
    hipLaunchKernelGGL(k_vote, bblk, dim3(NTHR), 0, stream,
                       indices, table, bitmap, B);
    hipLaunchKernelGGL(k_pass1, dim3(nblk), dim3(NTHR), 0, stream,
                       sb, lb, gb, bitmap, table, probs, labels, groups,
                       bsum, n, nblk);
    hipLaunchKernelGGL(k_scan, dim3(NBK), dim3(NTHR), 0, stream,
                       bsum, bpref, nblk);
    hipLaunchKernelGGL(k_pass2, dim3(nblk), dim3(NTHR), 0, stream,
                       sb, lb, gb, bitmap, table, probs, labels, groups,
                       bsum, bpref, acc_sum, acc_cnt, done, (float*)d_out,
                       n, nblk);
}

// Round 2
// 340.242 us; speedup vs baseline: 1.3926x; 1.3926x over previous
//
#include <hip/hip_runtime.h>
#include <hip/hip_bf16.h>

// ---------------------------------------------------------------------------
// DatasetScoreMatchingLoss — emulates np's fp32 sequential segment_sum via
// quantized contributions c_i = u*rint(x_i/u), u = ulp of the running-prefix
// binade, predicted per chunk by a linear model (exclusive chunk prefix +
// mean rate). Round 6: round-5 post-mortem showed (a) DS atomics serialize
// against the per-quad s_model ds_read via in-order lgkmcnt retirement
// (pass2 2.3x regression; pass1 fire-and-forget was neutral) -> REVERTED to
// round-4 plain read/add/write rows (bitwise-identical sums); (b) depth-1
// prefetch hides only ~140 of ~900 cy load latency -> depth-4 statically-
// indexed register prefetch ring in both passes (ITER stepped in groups of
// DEPTH so all slot indices are compile-time; no scratch).
// Arithmetic order (quad merge, reductions, scan, model, epilogue) unchanged
// from the verified 340us round-4 kernel.
// ---------------------------------------------------------------------------

#define TBL   65536u
#define TBLM  (TBL - 1u)
#define NGR   12            // actual group ids in [0,12)
#define NBK   24            // 12 groups x 2 labels
#define NCOL  25            // +1 dummy column (invalid / merged-away)
#define NTHR  256
#define CHUNK 16384
#define ITER  (CHUNK / 4 / NTHR)
#define DEPTH 4             // prefetch depth (ITER % DEPTH == 0)
#define MINC  10.0

__device__ __forceinline__ unsigned hash_idx(unsigned idx) {
    return (idx * 2654435761u) & TBLM;
}

// --- Phase 1: vote for last writer (max batch pos) + mark bitmap ------------
__global__ void k_vote(const int* __restrict__ indices,
                       unsigned long long* __restrict__ table,
                       unsigned* __restrict__ bitmap, int B) {
    int b = blockIdx.x * blockDim.x + threadIdx.x;
    if (b >= B) return;
    unsigned idx = (unsigned)indices[b];
    atomicOr(&bitmap[idx >> 5], 1u << (idx & 31u));
    unsigned long long key = ((unsigned long long)(idx + 1u)) << 32;
    unsigned long long val = key | (unsigned long long)(unsigned)b;
    unsigned slot = hash_idx(idx);
    for (;;) {
        unsigned long long prev = atomicCAS(&table[slot], 0ULL, val);
        if (prev == 0ULL) return;
        if ((prev >> 32) == (unsigned long long)(idx + 1u)) {
            atomicMax(&table[slot], val);
            return;
        }
        slot = (slot + 1u) & TBLM;
    }
}

// Resolve override directly from table + batch arrays (rare: ~32K/16.7M).
__device__ __forceinline__ void apply_ovr(int idx, float& s, int& l, int& g,
        const unsigned long long* __restrict__ table,
        const float* __restrict__ probs, const int* __restrict__ labels,
        const int* __restrict__ groups) {
    unsigned slot = hash_idx((unsigned)idx);
    unsigned hi = (unsigned)idx + 1u;
    for (;;) {
        unsigned long long e = table[slot];
        if ((unsigned)(e >> 32) == hi) {
            int b = (int)(e & 0xffffffffu);
            s = probs[b]; l = labels[b]; g = groups[b];
            return;
        }
        slot = (slot + 1u) & TBLM;
    }
}

// --- quad processing for pass1 (sum only): plain read/add/write rows --------
__device__ __forceinline__ void quad_p1(float* __restrict__ row,
        float4 s4, int4 l4, int4 g4, unsigned bits, int v,
        const unsigned long long* __restrict__ table,
        const float* __restrict__ probs, const int* __restrict__ labels,
        const int* __restrict__ groups) {
    float ss[4] = {s4.x, s4.y, s4.z, s4.w};
    int   ll[4] = {l4.x, l4.y, l4.z, l4.w};
    int   gg[4] = {g4.x, g4.y, g4.z, g4.w};
    float val[4]; int bkt[4];
#pragma unroll
    for (int e = 0; e < 4; ++e) {
        float s = ss[e]; int l = ll[e], g = gg[e];
        if ((bits >> e) & 1u)
            apply_ovr((v << 2) + e, s, l, g, table, probs, labels, groups);
        bool valid = (s == s) && ((unsigned)l < 2u) && ((unsigned)g < (unsigned)NGR);
        bkt[e] = valid ? (g * 2 + l) : NBK;
        val[e] = valid ? s : 0.f;
    }
    // merge intra-quad duplicates so 4 reads can batch before 4 writes
#define MRG(i, j) { bool m_ = (bkt[i] == bkt[j]); \
                    val[i] += m_ ? val[j] : 0.f;  \
                    bkt[j] = m_ ? NBK : bkt[j];   \
                    val[j] = m_ ? 0.f : val[j]; }
    MRG(0,1) MRG(0,2) MRG(0,3) MRG(1,2) MRG(1,3) MRG(2,3)
#undef MRG
    float a0 = row[bkt[0]], a1 = row[bkt[1]], a2 = row[bkt[2]], a3 = row[bkt[3]];
    row[bkt[0]] = a0 + val[0];
    row[bkt[1]] = a1 + val[1];
    row[bkt[2]] = a2 + val[2];
    row[bkt[3]] = a3 + val[3];
}

// --- Phase 2: per-chunk fp32 bucket sums (LDS slots) ------------------------
__global__ __launch_bounds__(NTHR) void k_pass1(
        const float* __restrict__ sb, const int* __restrict__ lb,
        const int* __restrict__ gb, const unsigned* __restrict__ bitmap,
        const unsigned long long* __restrict__ table,
        const float* __restrict__ probs, const int* __restrict__ labels,
        const int* __restrict__ groups,
        float* __restrict__ bsum, int n, int nblk) {
    __shared__ float s_acc[NTHR * NCOL];      // 25.6 KB
    int tid = threadIdx.x, blk = blockIdx.x;
    for (int i = tid; i < NTHR * NCOL; i += NTHR) s_acc[i] = 0.f;
    __syncthreads();
    float* row = &s_acc[tid * NCOL];
    int vbase = (blk * CHUNK) >> 2, nv = n >> 2;
    if (vbase + (CHUNK >> 2) <= nv) {
        // full chunk: depth-4 register prefetch ring, static slot indices
        int v0 = vbase + tid;
        float4 ps[DEPTH]; int4 pl[DEPTH], pg[DEPTH]; unsigned pb[DEPTH];
#pragma unroll
        for (int d = 0; d < DEPTH; ++d) {
            int v = v0 + d * NTHR;
            ps[d] = ((const float4*)sb)[v];
            pl[d] = ((const int4*)lb)[v];
            pg[d] = ((const int4*)gb)[v];
            pb[d] = bitmap[v >> 3];
        }
        unsigned sh = (unsigned)((v0 & 7) * 4);   // uniform per thread (NTHR%8==0)
        for (int it0 = 0; it0 < ITER; it0 += DEPTH) {
#pragma unroll
            for (int d = 0; d < DEPTH; ++d) {
                int it = it0 + d;
                int v = v0 + it * NTHR;
                float4 s4 = ps[d]; int4 l4 = pl[d], g4 = pg[d];
                unsigned bits = pb[d] >> sh;
                if (it + DEPTH < ITER) {          // issue slot refill early
                    int w = v + DEPTH * NTHR;
                    ps[d] = ((const float4*)sb)[w];
                    pl[d] = ((const int4*)lb)[w];
                    pg[d] = ((const int4*)gb)[w];
                    pb[d] = bitmap[w >> 3];
                }
                quad_p1(row, s4, l4, g4, bits, v, table, probs, labels, groups);
            }
        }
    } else {
        for (int it = 0; it < ITER; ++it) {
            int v = vbase + it * NTHR + tid;
            if (v >= nv) break;
            float4 s4 = ((const float4*)sb)[v];
            int4   l4 = ((const int4*)lb)[v];
            int4   g4 = ((const int4*)gb)[v];
            unsigned bits = bitmap[v >> 3] >> ((v & 7) * 4);
            quad_p1(row, s4, l4, g4, bits, v, table, probs, labels, groups);
        }
    }
    // scalar tail (n % 4) — last block only
    if (blk == nblk - 1) {
        for (int i = (nv << 2) + tid; i < n; i += NTHR) {
            float s = sb[i]; int l = lb[i], g = gb[i];
            if ((bitmap[i >> 5] >> (i & 31)) & 1u)
                apply_ovr(i, s, l, g, table, probs, labels, groups);
            bool valid = (s == s) && ((unsigned)l < 2u) && ((unsigned)g < (unsigned)NGR);
            int bk = valid ? (g * 2 + l) : NBK;
            row[bk] += valid ? s : 0.f;
        }
    }
    __syncthreads();
    if (tid < NBK * 8) {
        int bkt = tid >> 3, sub = tid & 7;
        float sm = 0.f;
        for (int j = 0; j < 32; ++j) sm += s_acc[(sub * 32 + j) * NCOL + bkt];
        for (int d = 4; d >= 1; d >>= 1) sm += __shfl_down(sm, d, 8);
        if (!sub) bsum[bkt * nblk + blk] = sm;
    }
}

// --- Phase 2.5: exclusive scan, one block per bucket (fp64) -----------------
__global__ void k_scan(const float* __restrict__ bsum,
                       float* __restrict__ bpref, int nblk) {
    __shared__ double sc[NTHR];
    int t = threadIdx.x, k = blockIdx.x;
    const float* src = bsum  + (size_t)k * nblk;
    float*       dst = bpref + (size_t)k * nblk;
    double carry = 0.0;
    for (int s0 = 0; s0 < nblk; s0 += 4 * NTHR) {
        int i0 = s0 + 4 * t;
        float x0 = (i0 + 0 < nblk) ? src[i0 + 0] : 0.f;
        float x1 = (i0 + 1 < nblk) ? src[i0 + 1] : 0.f;
        float x2 = (i0 + 2 < nblk) ? src[i0 + 2] : 0.f;
        float x3 = (i0 + 3 < nblk) ? src[i0 + 3] : 0.f;
        double p0 = (double)x0, p1 = p0 + x1, p2 = p1 + x2, tot = p2 + x3;
        sc[t] = tot;
        __syncthreads();
        for (int st = 1; st < NTHR; st <<= 1) {
            double a = (t >= st) ? sc[t - st] : 0.0;
            __syncthreads();
            sc[t] += a;
            __syncthreads();
        }
        double excl = carry + sc[t] - tot;
        if (i0 + 0 < nblk) dst[i0 + 0] = (float)excl;
        if (i0 + 1 < nblk) dst[i0 + 1] = (float)(excl + p0);
        if (i0 + 2 < nblk) dst[i0 + 2] = (float)(excl + p1);
        if (i0 + 3 < nblk) dst[i0 + 3] = (float)(excl + p2);
        double bt = sc[NTHR - 1];
        __syncthreads();
        carry += bt;
    }
}

__device__ __forceinline__ double aload_d(const double* p) {
    unsigned long long u = __hip_atomic_load((const unsigned long long*)p,
                              __ATOMIC_RELAXED, __HIP_MEMORY_SCOPE_AGENT);
    return __longlong_as_double((long long)u);
}

// --- quad processing for pass2: plain read/add/write float2 rows ------------
__device__ __forceinline__ void quad_p2(float2* __restrict__ row,
        const float2* __restrict__ s_model,
        float4 s4, int4 l4, int4 g4, unsigned bits, int v, int base,
        const unsigned long long* __restrict__ table,
        const float* __restrict__ probs, const int* __restrict__ labels,
        const int* __restrict__ groups) {
    float ss[4] = {s4.x, s4.y, s4.z, s4.w};
    int   ll[4] = {l4.x, l4.y, l4.z, l4.w};
    int   gg[4] = {g4.x, g4.y, g4.z, g4.w};
    float cv[4], cn[4]; int bkt[4];
#pragma unroll
    for (int e = 0; e < 4; ++e) {
        int idx = (v << 2) + e;
        float s = ss[e]; int l = ll[e], g = gg[e];
        if ((bits >> e) & 1u)
            apply_ovr(idx, s, l, g, table, probs, labels, groups);
        bool valid = (s == s) && ((unsigned)l < 2u) && ((unsigned)g < (unsigned)NGR);
        int bk = valid ? (g * 2 + l) : NBK;
        float2 m = s_model[bk];
        float S = fmaf(m.y, (float)(idx - base), m.x);
        float T = S + s;                          // post-add binade probe
        unsigned ue = __float_as_uint(T) & 0x7f800000u;
        float c;
        if (ue < (24u << 23)) c = s;              // tiny/zero prefix
        else {
            unsigned ub = ue - (23u << 23);       // u = ulp = 2^(e-150)
            float u    = __uint_as_float(ub);
            float uinv = __uint_as_float((254u << 23) - ub);
            c = u * rintf(s * uinv);
        }
        bkt[e] = bk;
        cv[e] = valid ? c : 0.f;
        cn[e] = valid ? 1.f : 0.f;
    }
#define MRG(i, j) { bool m_ = (bkt[i] == bkt[j]); \
                    cv[i] += m_ ? cv[j] : 0.f;    \
                    cn[i] += m_ ? cn[j] : 0.f;    \
                    bkt[j] = m_ ? NBK : bkt[j];   \
                    cv[j] = m_ ? 0.f : cv[j];     \
                    cn[j] = m_ ? 0.f : cn[j]; }
    MRG(0,1) MRG(0,2) MRG(0,3) MRG(1,2) MRG(1,3) MRG(2,3)
#undef MRG
    float2 a0 = row[bkt[0]], a1 = row[bkt[1]], a2 = row[bkt[2]], a3 = row[bkt[3]];
    a0.x += cv[0]; a0.y += cn[0];
    a1.x += cv[1]; a1.y += cn[1];
    a2.x += cv[2]; a2.y += cn[2];
    a3.x += cv[3]; a3.y += cn[3];
    row[bkt[0]] = a0; row[bkt[1]] = a1; row[bkt[2]] = a2; row[bkt[3]] = a3;
}

// --- Phase 3: quantized contributions + counts (LDS float2 slots) -----------
// Last block to finish runs the fp64 epilogue and writes out[0].
__global__ __launch_bounds__(NTHR) void k_pass2(
        const float* __restrict__ sb, const int* __restrict__ lb,
        const int* __restrict__ gb, const unsigned* __restrict__ bitmap,
        const unsigned long long* __restrict__ table,
        const float* __restrict__ probs, const int* __restrict__ labels,
        const int* __restrict__ groups,
        const float* __restrict__ bsum, const float* __restrict__ bpref,
        double* __restrict__ acc_sum, double* __restrict__ acc_cnt,
        unsigned* __restrict__ done, float* __restrict__ out,
        int n, int nblk) {
    __shared__ float2 s_acc[NTHR * NCOL];     // 51.2 KB: (c_sum, count)
    __shared__ float2 s_model[NCOL];          // (excl_prefix, rate)
    int tid = threadIdx.x, blk = blockIdx.x;
    for (int i = tid; i < NTHR * NCOL; i += NTHR) s_acc[i] = make_float2(0.f, 0.f);
    if (tid < NBK)
        s_model[tid] = make_float2(bpref[tid * nblk + blk],
                                   bsum[tid * nblk + blk] * (1.0f / CHUNK));
    if (tid == NBK) s_model[NBK] = make_float2(0.f, 0.f);
    __syncthreads();
    float2* row = &s_acc[tid * NCOL];
    int base = blk * CHUNK;
    int vbase = base >> 2, nv = n >> 2;
    if (vbase + (CHUNK >> 2) <= nv) {
        // full chunk: depth-4 register prefetch ring, static slot indices
        int v0 = vbase + tid;
        float4 ps[DEPTH]; int4 pl[DEPTH], pg[DEPTH]; unsigned pb[DEPTH];
#pragma unroll
        for (int d = 0; d < DEPTH; ++d) {
            int v = v0 + d * NTHR;
            ps[d] = ((const float4*)sb)[v];
            pl[d] = ((const int4*)lb)[v];
            pg[d] = ((const int4*)gb)[v];
            pb[d] = bitmap[v >> 3];
        }
        unsigned sh = (unsigned)((v0 & 7) * 4);   // uniform per thread
        for (int it0 = 0; it0 < ITER; it0 += DEPTH) {
#pragma unroll
            for (int d = 0; d < DEPTH; ++d) {
                int it = it0 + d;
                int v = v0 + it * NTHR;
                float4 s4 = ps[d]; int4 l4 = pl[d], g4 = pg[d];
                unsigned bits = pb[d] >> sh;
                if (it + DEPTH < ITER) {          // issue slot refill early
                    int w = v + DEPTH * NTHR;
                    ps[d] = ((const float4*)sb)[w];
                    pl[d] = ((const int4*)lb)[w];
                    pg[d] = ((const int4*)gb)[w];
                    pb[d] = bitmap[w >> 3];
                }
                quad_p2(row, s_model, s4, l4, g4, bits, v, base,
                        table, probs, labels, groups);
            }
        }
    } else {
        for (int it = 0; it < ITER; ++it) {
            int v = vbase + it * NTHR + tid;
            if (v >= nv) break;
            float4 s4 = ((const float4*)sb)[v];
            int4   l4 = ((const int4*)lb)[v];
            int4   g4 = ((const int4*)gb)[v];
            unsigned bits = bitmap[v >> 3] >> ((v & 7) * 4);
            quad_p2(row, s_model, s4, l4, g4, bits, v, base,
                    table, probs, labels, groups);
        }
    }
    if (blk == nblk - 1) {                            // scalar tail
        for (int i = (nv << 2) + tid; i < n; i += NTHR) {
            float s = sb[i]; int l = lb[i], g = gb[i];
            if ((bitmap[i >> 5] >> (i & 31)) & 1u)
                apply_ovr(i, s, l, g, table, probs, labels, groups);
            bool valid = (s == s) && ((unsigned)l < 2u) && ((unsigned)g < (unsigned)NGR);
            int bk = valid ? (g * 2 + l) : NBK;
            float2 m = s_model[bk];
            float S = fmaf(m.y, (float)(i - base), m.x);
            float T = S + s;
            unsigned ue = __float_as_uint(T) & 0x7f800000u;
            float c;
            if (ue < (24u << 23)) c = s;
            else {
                unsigned ub = ue - (23u << 23);
                float u    = __uint_as_float(ub);
                float uinv = __uint_as_float((254u << 23) - ub);
                c = u * rintf(s * uinv);
            }
            float2 a = row[bk];
            a.x += valid ? c : 0.f;
            a.y += valid ? 1.f : 0.f;
            row[bk] = a;
        }
    }
    __syncthreads();
    if (tid < NBK * 8) {
        int bkt = tid >> 3, sub = tid & 7;
        float sm = 0.f, cc = 0.f;
        for (int j = 0; j < 32; ++j) {
            float2 a = s_acc[(sub * 32 + j) * NCOL + bkt];
            sm += a.x; cc += a.y;
        }
        for (int d = 4; d >= 1; d >>= 1) {
            sm += __shfl_down(sm, d, 8);
            cc += __shfl_down(cc, d, 8);
        }
        if (!sub) {
            atomicAdd(&acc_sum[bkt], (double)sm);
            atomicAdd(&acc_cnt[bkt], (double)cc);
        }
    }
    __syncthreads();
    if (tid == 0) {
        __threadfence();
        unsigned r = __hip_atomic_fetch_add(done, 1u, __ATOMIC_ACQ_REL,
                                            __HIP_MEMORY_SCOPE_AGENT);
        if (r == (unsigned)(gridDim.x - 1)) {         // last block: epilogue
            double var[2], nn[2];
            for (int l = 0; l < 2; ++l) {
                double avg[NGR];
                double ncnt = 0.0, s = 0.0;
                for (int g = 0; g < NGR; ++g) {
                    double c  = aload_d(&acc_cnt[g * 2 + l]);
                    double sm = aload_d(&acc_sum[g * 2 + l]);
                    double a = sm / fmax(c, 1.0);
                    avg[g] = a;
                    if (c >= MINC) { ncnt += 1.0; s += a; }
                }
                double mean = s / fmax(ncnt, 1.0), v = 0.0;
                for (int g = 0; g < NGR; ++g) {
                    double c = aload_d(&acc_cnt[g * 2 + l]);
                    if (c >= MINC) { double d = avg[g] - mean; v += d * d; }
                }
                var[l] = v / fmax(ncnt - 1.0, 1.0);
                nn[l] = ncnt;
            }
            bool p = nn[1] >= 2.0, q = nn[0] >= 2.0;
            double loss = (p && q) ? 0.5 * (var[1] + var[0])
                        : (p ? var[1] : (q ? var[0] : 0.0));
            out[0] = (float)loss;
        }
    }
}

extern "C" void kernel_launch(void* const* d_in, const int* in_sizes, int n_in,
                              void* d_out, int out_size, void* d_ws, size_t ws_size,
                              hipStream_t stream) {
    const float* probs   = (const float*)d_in[0];
    const int*   labels  = (const int*)d_in[1];
    const int*   groups  = (const int*)d_in[2];
    const int*   indices = (const int*)d_in[3];
    const float* sb      = (const float*)d_in[4];
    const int*   lb      = (const int*)d_in[5];
    const int*   gb      = (const int*)d_in[6];
    int B = in_sizes[0];
    int n = in_sizes[4];
    int nblk   = (n + CHUNK - 1) / CHUNK;
    int nwords = (n + 31) / 32;

    // ws layout: [zeroed: table | bitmap | acc_sum | acc_cnt | done][rest]
    char* ws = (char*)d_ws;
    size_t off = 0;
    unsigned long long* table = (unsigned long long*)(ws + off); off += (size_t)TBL * 8;
    unsigned* bitmap  = (unsigned*)(ws + off); off += (size_t)nwords * 4;
    double*   acc_sum = (double*)(ws + off);   off += NBK * 8;
    double*   acc_cnt = (double*)(ws + off);   off += NBK * 8;
    unsigned* done    = (unsigned*)(ws + off); off += 8;
    size_t zero_bytes = off;
    float*    bsum    = (float*)(ws + off);    off += (size_t)nblk * NBK * 4;
    float*    bpref   = (float*)(ws + off);    off += (size_t)nblk * NBK * 4;

    hipMemsetAsync(d_ws, 0, zero_bytes, stream);

    dim3 bblk((B + NTHR - 1) / NTHR);
    hipLaunchKernelGGL(k_vote, bblk, dim3(NTHR), 0, stream,
                       indices, table, bitmap, B);
    hipLaunchKernelGGL(k_pass1, dim3(nblk), dim3(NTHR), 0, stream,
                       sb, lb, gb, bitmap, table, probs, labels, groups,
                       bsum, n, nblk);
    hipLaunchKernelGGL(k_scan, dim3(NBK), dim3(NTHR), 0, stream,
                       bsum, bpref, nblk);
    hipLaunchKernelGGL(k_pass2, dim3(nblk), dim3(NTHR), 0, stream,
                       sb, lb, gb, bitmap, table, probs, labels, groups,
                       bsum, bpref, acc_sum, acc_cnt, done, (float*)d_out,
                       n, nblk);
}

// Round 3
// 334.717 us; speedup vs baseline: 1.4156x; 1.0165x over previous
//
#include <hip/hip_runtime.h>
#include <hip/hip_bf16.h>

// ---------------------------------------------------------------------------
// DatasetScoreMatchingLoss — emulates np's fp32 sequential segment_sum via
// quantized contributions c_i = u*rint(x_i/u), u = ulp of the running-prefix
// binade, predicted per chunk by a linear model (exclusive chunk prefix +
// mean rate). Round 7: round-6 showed VGPR stuck at 84 -> compiler SANK the
// depth-4 prefetch ring back to uses (silent revert). This round:
// (a) asm volatile memory barrier per iteration pins refill loads DEPTH=4
//     ahead (illegal for compiler to move loads across a memory clobber);
//     loop fully unrolled so ring indices are static.
// (b) k_resolve pre-expands the winner hash table into 16-B records
//     {s,l,g,idx+1} so the hot-loop override path is ONE dwordx4 probe
//     (was: table walk + 3 scattered loads). Same probe sequence, same
//     values -> bit-identical output.
// Accumulation arithmetic (quad merge, LDS rows, reductions, scan, model,
// epilogue) unchanged from the verified 340us round-4 kernel.
// ---------------------------------------------------------------------------

#define TBL   65536u
#define TBLM  (TBL - 1u)
#define NGR   12            // actual group ids in [0,12)
#define NBK   24            // 12 groups x 2 labels
#define NCOL  25            // +1 dummy column (invalid / merged-away)
#define NTHR  256
#define CHUNK 16384
#define ITER  (CHUNK / 4 / NTHR)
#define DEPTH 4             // prefetch depth (ITER % DEPTH == 0)
#define MINC  10.0

__device__ __forceinline__ unsigned hash_idx(unsigned idx) {
    return (idx * 2654435761u) & TBLM;
}

// --- Phase 1: vote for last writer (max batch pos) + mark bitmap ------------
__global__ void k_vote(const int* __restrict__ indices,
                       unsigned long long* __restrict__ table,
                       unsigned* __restrict__ bitmap, int B) {
    int b = blockIdx.x * blockDim.x + threadIdx.x;
    if (b >= B) return;
    unsigned idx = (unsigned)indices[b];
    atomicOr(&bitmap[idx >> 5], 1u << (idx & 31u));
    unsigned long long key = ((unsigned long long)(idx + 1u)) << 32;
    unsigned long long val = key | (unsigned long long)(unsigned)b;
    unsigned slot = hash_idx(idx);
    for (;;) {
        unsigned long long prev = atomicCAS(&table[slot], 0ULL, val);
        if (prev == 0ULL) return;
        if ((prev >> 32) == (unsigned long long)(idx + 1u)) {
            atomicMax(&table[slot], val);
            return;
        }
        slot = (slot + 1u) & TBLM;
    }
}

// --- Phase 1.5: expand winners into single-load records ---------------------
// tbl2[slot] = {score, label(bits), group(bits), idx+1(bits)}; empty -> w=0.
__global__ void k_resolve(const unsigned long long* __restrict__ table,
                          const float* __restrict__ probs,
                          const int* __restrict__ labels,
                          const int* __restrict__ groups,
                          float4* __restrict__ tbl2) {
    int s = blockIdx.x * blockDim.x + threadIdx.x;
    unsigned long long e = table[s];
    unsigned hi = (unsigned)(e >> 32);
    float4 r = make_float4(0.f, 0.f, 0.f, 0.f);
    if (hi) {
        int b = (int)(e & 0xffffffffu);
        r.x = probs[b];
        r.y = __int_as_float(labels[b]);
        r.z = __int_as_float(groups[b]);
        r.w = __uint_as_float(hi);
    }
    tbl2[s] = r;
}

// Resolve override with a single 16-B probe (rare: ~32K/16.7M elements).
__device__ __forceinline__ void apply_ovr(int idx, float& s, int& l, int& g,
        const float4* __restrict__ tbl2) {
    unsigned slot = hash_idx((unsigned)idx);
    unsigned hi = (unsigned)idx + 1u;
    for (;;) {
        float4 r = tbl2[slot];
        if (__float_as_uint(r.w) == hi) {
            s = r.x; l = __float_as_int(r.y); g = __float_as_int(r.z);
            return;
        }
        slot = (slot + 1u) & TBLM;
    }
}

// --- quad processing for pass1 (sum only): plain read/add/write rows --------
__device__ __forceinline__ void quad_p1(float* __restrict__ row,
        float4 s4, int4 l4, int4 g4, unsigned bits, int v,
        const float4* __restrict__ tbl2) {
    float ss[4] = {s4.x, s4.y, s4.z, s4.w};
    int   ll[4] = {l4.x, l4.y, l4.z, l4.w};
    int   gg[4] = {g4.x, g4.y, g4.z, g4.w};
    float val[4]; int bkt[4];
#pragma unroll
    for (int e = 0; e < 4; ++e) {
        float s = ss[e]; int l = ll[e], g = gg[e];
        if ((bits >> e) & 1u)
            apply_ovr((v << 2) + e, s, l, g, tbl2);
        bool valid = (s == s) && ((unsigned)l < 2u) && ((unsigned)g < (unsigned)NGR);
        bkt[e] = valid ? (g * 2 + l) : NBK;
        val[e] = valid ? s : 0.f;
    }
    // merge intra-quad duplicates so 4 reads can batch before 4 writes
#define MRG(i, j) { bool m_ = (bkt[i] == bkt[j]); \
                    val[i] += m_ ? val[j] : 0.f;  \
                    bkt[j] = m_ ? NBK : bkt[j];   \
                    val[j] = m_ ? 0.f : val[j]; }
    MRG(0,1) MRG(0,2) MRG(0,3) MRG(1,2) MRG(1,3) MRG(2,3)
#undef MRG
    float a0 = row[bkt[0]], a1 = row[bkt[1]], a2 = row[bkt[2]], a3 = row[bkt[3]];
    row[bkt[0]] = a0 + val[0];
    row[bkt[1]] = a1 + val[1];
    row[bkt[2]] = a2 + val[2];
    row[bkt[3]] = a3 + val[3];
}

// --- Phase 2: per-chunk fp32 bucket sums (LDS slots) ------------------------
__global__ __launch_bounds__(NTHR) void k_pass1(
        const float* __restrict__ sb, const int* __restrict__ lb,
        const int* __restrict__ gb, const unsigned* __restrict__ bitmap,
        const float4* __restrict__ tbl2,
        float* __restrict__ bsum, int n, int nblk) {
    __shared__ float s_acc[NTHR * NCOL];      // 25.6 KB
    int tid = threadIdx.x, blk = blockIdx.x;
    for (int i = tid; i < NTHR * NCOL; i += NTHR) s_acc[i] = 0.f;
    __syncthreads();
    float* row = &s_acc[tid * NCOL];
    int vbase = (blk * CHUNK) >> 2, nv = n >> 2;
    if (vbase + (CHUNK >> 2) <= nv) {
        // full chunk: depth-4 prefetch ring, pinned by memory-clobber asm
        int v0 = vbase + tid;
        float4 ps[DEPTH]; int4 pl[DEPTH], pg[DEPTH]; unsigned pb[DEPTH];
#pragma unroll
        for (int d = 0; d < DEPTH; ++d) {
            int v = v0 + d * NTHR;
            ps[d] = ((const float4*)sb)[v];
            pl[d] = ((const int4*)lb)[v];
            pg[d] = ((const int4*)gb)[v];
            pb[d] = bitmap[v >> 3];
        }
        unsigned sh = (unsigned)((v0 & 7) * 4);   // uniform per thread
#pragma unroll
        for (int it = 0; it < ITER; ++it) {
            int d = it & (DEPTH - 1);             // static after full unroll
            int v = v0 + it * NTHR;
            float4 s4 = ps[d]; int4 l4 = pl[d], g4 = pg[d];
            unsigned bits = pb[d] >> sh;
            if (it + DEPTH < ITER) {              // refill slot DEPTH ahead
                int w = v + DEPTH * NTHR;
                ps[d] = ((const float4*)sb)[w];
                pl[d] = ((const int4*)lb)[w];
                pg[d] = ((const int4*)gb)[w];
                pb[d] = bitmap[w >> 3];
            }
            asm volatile("" ::: "memory");        // refills may not sink below
            quad_p1(row, s4, l4, g4, bits, v, tbl2);
        }
    } else {
        for (int it = 0; it < ITER; ++it) {
            int v = vbase + it * NTHR + tid;
            if (v >= nv) break;
            float4 s4 = ((const float4*)sb)[v];
            int4   l4 = ((const int4*)lb)[v];
            int4   g4 = ((const int4*)gb)[v];
            unsigned bits = bitmap[v >> 3] >> ((v & 7) * 4);
            quad_p1(row, s4, l4, g4, bits, v, tbl2);
        }
    }
    // scalar tail (n % 4) — last block only
    if (blk == nblk - 1) {
        for (int i = (nv << 2) + tid; i < n; i += NTHR) {
            float s = sb[i]; int l = lb[i], g = gb[i];
            if ((bitmap[i >> 5] >> (i & 31)) & 1u)
                apply_ovr(i, s, l, g, tbl2);
            bool valid = (s == s) && ((unsigned)l < 2u) && ((unsigned)g < (unsigned)NGR);
            int bk = valid ? (g * 2 + l) : NBK;
            row[bk] += valid ? s : 0.f;
        }
    }
    __syncthreads();
    if (tid < NBK * 8) {
        int bkt = tid >> 3, sub = tid & 7;
        float sm = 0.f;
        for (int j = 0; j < 32; ++j) sm += s_acc[(sub * 32 + j) * NCOL + bkt];
        for (int d = 4; d >= 1; d >>= 1) sm += __shfl_down(sm, d, 8);
        if (!sub) bsum[bkt * nblk + blk] = sm;
    }
}

// --- Phase 2.5: exclusive scan, one block per bucket (fp64) -----------------
__global__ void k_scan(const float* __restrict__ bsum,
                       float* __restrict__ bpref, int nblk) {
    __shared__ double sc[NTHR];
    int t = threadIdx.x, k = blockIdx.x;
    const float* src = bsum  + (size_t)k * nblk;
    float*       dst = bpref + (size_t)k * nblk;
    double carry = 0.0;
    for (int s0 = 0; s0 < nblk; s0 += 4 * NTHR) {
        int i0 = s0 + 4 * t;
        float x0 = (i0 + 0 < nblk) ? src[i0 + 0] : 0.f;
        float x1 = (i0 + 1 < nblk) ? src[i0 + 1] : 0.f;
        float x2 = (i0 + 2 < nblk) ? src[i0 + 2] : 0.f;
        float x3 = (i0 + 3 < nblk) ? src[i0 + 3] : 0.f;
        double p0 = (double)x0, p1 = p0 + x1, p2 = p1 + x2, tot = p2 + x3;
        sc[t] = tot;
        __syncthreads();
        for (int st = 1; st < NTHR; st <<= 1) {
            double a = (t >= st) ? sc[t - st] : 0.0;
            __syncthreads();
            sc[t] += a;
            __syncthreads();
        }
        double excl = carry + sc[t] - tot;
        if (i0 + 0 < nblk) dst[i0 + 0] = (float)excl;
        if (i0 + 1 < nblk) dst[i0 + 1] = (float)(excl + p0);
        if (i0 + 2 < nblk) dst[i0 + 2] = (float)(excl + p1);
        if (i0 + 3 < nblk) dst[i0 + 3] = (float)(excl + p2);
        double bt = sc[NTHR - 1];
        __syncthreads();
        carry += bt;
    }
}

__device__ __forceinline__ double aload_d(const double* p) {
    unsigned long long u = __hip_atomic_load((const unsigned long long*)p,
                              __ATOMIC_RELAXED, __HIP_MEMORY_SCOPE_AGENT);
    return __longlong_as_double((long long)u);
}

// --- quad processing for pass2: plain read/add/write float2 rows ------------
__device__ __forceinline__ void quad_p2(float2* __restrict__ row,
        const float2* __restrict__ s_model,
        float4 s4, int4 l4, int4 g4, unsigned bits, int v, int base,
        const float4* __restrict__ tbl2) {
    float ss[4] = {s4.x, s4.y, s4.z, s4.w};
    int   ll[4] = {l4.x, l4.y, l4.z, l4.w};
    int   gg[4] = {g4.x, g4.y, g4.z, g4.w};
    float cv[4], cn[4]; int bkt[4];
#pragma unroll
    for (int e = 0; e < 4; ++e) {
        int idx = (v << 2) + e;
        float s = ss[e]; int l = ll[e], g = gg[e];
        if ((bits >> e) & 1u)
            apply_ovr(idx, s, l, g, tbl2);
        bool valid = (s == s) && ((unsigned)l < 2u) && ((unsigned)g < (unsigned)NGR);
        int bk = valid ? (g * 2 + l) : NBK;
        float2 m = s_model[bk];
        float S = fmaf(m.y, (float)(idx - base), m.x);
        float T = S + s;                          // post-add binade probe
        unsigned ue = __float_as_uint(T) & 0x7f800000u;
        float c;
        if (ue < (24u << 23)) c = s;              // tiny/zero prefix
        else {
            unsigned ub = ue - (23u << 23);       // u = ulp = 2^(e-150)
            float u    = __uint_as_float(ub);
            float uinv = __uint_as_float((254u << 23) - ub);
            c = u * rintf(s * uinv);
        }
        bkt[e] = bk;
        cv[e] = valid ? c : 0.f;
        cn[e] = valid ? 1.f : 0.f;
    }
#define MRG(i, j) { bool m_ = (bkt[i] == bkt[j]); \
                    cv[i] += m_ ? cv[j] : 0.f;    \
                    cn[i] += m_ ? cn[j] : 0.f;    \
                    bkt[j] = m_ ? NBK : bkt[j];   \
                    cv[j] = m_ ? 0.f : cv[j];     \
                    cn[j] = m_ ? 0.f : cn[j]; }
    MRG(0,1) MRG(0,2) MRG(0,3) MRG(1,2) MRG(1,3) MRG(2,3)
#undef MRG
    float2 a0 = row[bkt[0]], a1 = row[bkt[1]], a2 = row[bkt[2]], a3 = row[bkt[3]];
    a0.x += cv[0]; a0.y += cn[0];
    a1.x += cv[1]; a1.y += cn[1];
    a2.x += cv[2]; a2.y += cn[2];
    a3.x += cv[3]; a3.y += cn[3];
    row[bkt[0]] = a0; row[bkt[1]] = a1; row[bkt[2]] = a2; row[bkt[3]] = a3;
}

// --- Phase 3: quantized contributions + counts (LDS float2 slots) -----------
// Last block to finish runs the fp64 epilogue and writes out[0].
__global__ __launch_bounds__(NTHR) void k_pass2(
        const float* __restrict__ sb, const int* __restrict__ lb,
        const int* __restrict__ gb, const unsigned* __restrict__ bitmap,
        const float4* __restrict__ tbl2,
        const float* __restrict__ bsum, const float* __restrict__ bpref,
        double* __restrict__ acc_sum, double* __restrict__ acc_cnt,
        unsigned* __restrict__ done, float* __restrict__ out,
        int n, int nblk) {
    __shared__ float2 s_acc[NTHR * NCOL];     // 51.2 KB: (c_sum, count)
    __shared__ float2 s_model[NCOL];          // (excl_prefix, rate)
    int tid = threadIdx.x, blk = blockIdx.x;
    for (int i = tid; i < NTHR * NCOL; i += NTHR) s_acc[i] = make_float2(0.f, 0.f);
    if (tid < NBK)
        s_model[tid] = make_float2(bpref[tid * nblk + blk],
                                   bsum[tid * nblk + blk] * (1.0f / CHUNK));
    if (tid == NBK) s_model[NBK] = make_float2(0.f, 0.f);
    __syncthreads();
    float2* row = &s_acc[tid * NCOL];
    int base = blk * CHUNK;
    int vbase = base >> 2, nv = n >> 2;
    if (vbase + (CHUNK >> 2) <= nv) {
        // full chunk: depth-4 prefetch ring, pinned by memory-clobber asm
        int v0 = vbase + tid;
        float4 ps[DEPTH]; int4 pl[DEPTH], pg[DEPTH]; unsigned pb[DEPTH];
#pragma unroll
        for (int d = 0; d < DEPTH; ++d) {
            int v = v0 + d * NTHR;
            ps[d] = ((const float4*)sb)[v];
            pl[d] = ((const int4*)lb)[v];
            pg[d] = ((const int4*)gb)[v];
            pb[d] = bitmap[v >> 3];
        }
        unsigned sh = (unsigned)((v0 & 7) * 4);   // uniform per thread
#pragma unroll
        for (int it = 0; it < ITER; ++it) {
            int d = it & (DEPTH - 1);             // static after full unroll
            int v = v0 + it * NTHR;
            float4 s4 = ps[d]; int4 l4 = pl[d], g4 = pg[d];
            unsigned bits = pb[d] >> sh;
            if (it + DEPTH < ITER) {              // refill slot DEPTH ahead
                int w = v + DEPTH * NTHR;
                ps[d] = ((const float4*)sb)[w];
                pl[d] = ((const int4*)lb)[w];
                pg[d] = ((const int4*)gb)[w];
                pb[d] = bitmap[w >> 3];
            }
            asm volatile("" ::: "memory");        // refills may not sink below
            quad_p2(row, s_model, s4, l4, g4, bits, v, base, tbl2);
        }
    } else {
        for (int it = 0; it < ITER; ++it) {
            int v = vbase + it * NTHR + tid;
            if (v >= nv) break;
            float4 s4 = ((const float4*)sb)[v];
            int4   l4 = ((const int4*)lb)[v];
            int4   g4 = ((const int4*)gb)[v];
            unsigned bits = bitmap[v >> 3] >> ((v & 7) * 4);
            quad_p2(row, s_model, s4, l4, g4, bits, v, base, tbl2);
        }
    }
    if (blk == nblk - 1) {                            // scalar tail
        for (int i = (nv << 2) + tid; i < n; i += NTHR) {
            float s = sb[i]; int l = lb[i], g = gb[i];
            if ((bitmap[i >> 5] >> (i & 31)) & 1u)
                apply_ovr(i, s, l, g, tbl2);
            bool valid = (s == s) && ((unsigned)l < 2u) && ((unsigned)g < (unsigned)NGR);
            int bk = valid ? (g * 2 + l) : NBK;
            float2 m = s_model[bk];
            float S = fmaf(m.y, (float)(i - base), m.x);
            float T = S + s;
            unsigned ue = __float_as_uint(T) & 0x7f800000u;
            float c;
            if (ue < (24u << 23)) c = s;
            else {
                unsigned ub = ue - (23u << 23);
                float u    = __uint_as_float(ub);
                float uinv = __uint_as_float((254u << 23) - ub);
                c = u * rintf(s * uinv);
            }
            float2 a = row[bk];
            a.x += valid ? c : 0.f;
            a.y += valid ? 1.f : 0.f;
            row[bk] = a;
        }
    }
    __syncthreads();
    if (tid < NBK * 8) {
        int bkt = tid >> 3, sub = tid & 7;
        float sm = 0.f, cc = 0.f;
        for (int j = 0; j < 32; ++j) {
            float2 a = s_acc[(sub * 32 + j) * NCOL + bkt];
            sm += a.x; cc += a.y;
        }
        for (int d = 4; d >= 1; d >>= 1) {
            sm += __shfl_down(sm, d, 8);
            cc += __shfl_down(cc, d, 8);
        }
        if (!sub) {
            atomicAdd(&acc_sum[bkt], (double)sm);
            atomicAdd(&acc_cnt[bkt], (double)cc);
        }
    }
    __syncthreads();
    if (tid == 0) {
        __threadfence();
        unsigned r = __hip_atomic_fetch_add(done, 1u, __ATOMIC_ACQ_REL,
                                            __HIP_MEMORY_SCOPE_AGENT);
        if (r == (unsigned)(gridDim.x - 1)) {         // last block: epilogue
            double var[2], nn[2];
            for (int l = 0; l < 2; ++l) {
                double avg[NGR];
                double ncnt = 0.0, s = 0.0;
                for (int g = 0; g < NGR; ++g) {
                    double c  = aload_d(&acc_cnt[g * 2 + l]);
                    double sm = aload_d(&acc_sum[g * 2 + l]);
                    double a = sm / fmax(c, 1.0);
                    avg[g] = a;
                    if (c >= MINC) { ncnt += 1.0; s += a; }
                }
                double mean = s / fmax(ncnt, 1.0), v = 0.0;
                for (int g = 0; g < NGR; ++g) {
                    double c = aload_d(&acc_cnt[g * 2 + l]);
                    if (c >= MINC) { double d = avg[g] - mean; v += d * d; }
                }
                var[l] = v / fmax(ncnt - 1.0, 1.0);
                nn[l] = ncnt;
            }
            bool p = nn[1] >= 2.0, q = nn[0] >= 2.0;
            double loss = (p && q) ? 0.5 * (var[1] + var[0])
                        : (p ? var[1] : (q ? var[0] : 0.0));
            out[0] = (float)loss;
        }
    }
}

extern "C" void kernel_launch(void* const* d_in, const int* in_sizes, int n_in,
                              void* d_out, int out_size, void* d_ws, size_t ws_size,
                              hipStream_t stream) {
    const float* probs   = (const float*)d_in[0];
    const int*   labels  = (const int*)d_in[1];
    const int*   groups  = (const int*)d_in[2];
    const int*   indices = (const int*)d_in[3];
    const float* sb      = (const float*)d_in[4];
    const int*   lb      = (const int*)d_in[5];
    const int*   gb      = (const int*)d_in[6];
    int B = in_sizes[0];
    int n = in_sizes[4];
    int nblk   = (n + CHUNK - 1) / CHUNK;
    int nwords = (n + 31) / 32;

    // ws layout: [zeroed: table | bitmap | acc_sum | acc_cnt | done]
    //            [unzeroed: tbl2 | bsum | bpref]
    char* ws = (char*)d_ws;
    size_t off = 0;
    unsigned long long* table = (unsigned long long*)(ws + off); off += (size_t)TBL * 8;
    unsigned* bitmap  = (unsigned*)(ws + off); off += (size_t)nwords * 4;
    double*   acc_sum = (double*)(ws + off);   off += NBK * 8;
    double*   acc_cnt = (double*)(ws + off);   off += NBK * 8;
    unsigned* done    = (unsigned*)(ws + off); off += 8;
    size_t zero_bytes = off;
    float4*   tbl2    = (float4*)(ws + off);   off += (size_t)TBL * 16;
    float*    bsum    = (float*)(ws + off);    off += (size_t)nblk * NBK * 4;
    float*    bpref   = (float*)(ws + off);    off += (size_t)nblk * NBK * 4;

    hipMemsetAsync(d_ws, 0, zero_bytes, stream);

    dim3 bblk((B + NTHR - 1) / NTHR);
    hipLaunchKernelGGL(k_vote, bblk, dim3(NTHR), 0, stream,
                       indices, table, bitmap, B);
    hipLaunchKernelGGL(k_resolve, dim3(TBL / NTHR), dim3(NTHR), 0, stream,
                       table, probs, labels, groups, tbl2);
    hipLaunchKernelGGL(k_pass1, dim3(nblk), dim3(NTHR), 0, stream,
                       sb, lb, gb, bitmap, tbl2, bsum, n, nblk);
    hipLaunchKernelGGL(k_scan, dim3(NBK), dim3(NTHR), 0, stream,
                       bsum, bpref, nblk);
    hipLaunchKernelGGL(k_pass2, dim3(nblk), dim3(NTHR), 0, stream,
                       sb, lb, gb, bitmap, tbl2, bsum, bpref,
                       acc_sum, acc_cnt, done, (float*)d_out, n, nblk);
}